// Round 5
// baseline (613.244 us; speedup 1.0000x reference)
//
#include <hip/hip_runtime.h>

// Persistent-kernel Sinkhorn (scaling form), fence-free grid barrier.
// Cross-block data (y, psum/tsum, barrier) uses relaxed AGENT-scope atomics
// (sc0 sc1 -> LLC-coherent, no L2 wbinv walks). K = exp(-C/eps) is a
// block-PRIVATE global stripe -> stays dirty/resident in XCD L2 all passes.
//   a' = m_src .* a ./ (a .* (K b) + 1e-6);  b' = m_tgt .* b ./ (b .* (K a') + 1e-6)
//   cost_b = sum_i a_i * sum_j (K.C)_ij b_j   (K.C recomputed from C)

#define SN 2304
#define SNF4 576
#define NBAT 32
#define ROWS 9
#define NBLK 256
#define NTHR 512
#define WPW 9        // 32-j windows per wave (8 waves x 9 x 32 = 2304)

typedef unsigned long long u64;

__device__ __forceinline__ void fma4(float4& a, float k, const float4 x) {
    a.x = fmaf(k, x.x, a.x);
    a.y = fmaf(k, x.y, a.y);
    a.z = fmaf(k, x.z, a.z);
    a.w = fmaf(k, x.w, a.w);
}

// ---- LLC-coherent (agent-scope, relaxed) access helpers: no fences ----
__device__ __forceinline__ float4 ldg_llc4(const float4* p) {
    const u64* q = (const u64*)p;
    u64 lo = __hip_atomic_load(q, __ATOMIC_RELAXED, __HIP_MEMORY_SCOPE_AGENT);
    u64 hi = __hip_atomic_load(q + 1, __ATOMIC_RELAXED, __HIP_MEMORY_SCOPE_AGENT);
    float4 v;
    ((u64*)&v)[0] = lo;
    ((u64*)&v)[1] = hi;
    return v;
}
__device__ __forceinline__ float ldg_llc(const float* p) {
    unsigned int u = __hip_atomic_load((const unsigned int*)p,
                                       __ATOMIC_RELAXED, __HIP_MEMORY_SCOPE_AGENT);
    float f;
    *(unsigned int*)&f = u;
    return f;
}
__device__ __forceinline__ void stg_llc(float* p, float v) {
    unsigned int u = *(unsigned int*)&v;
    __hip_atomic_store((unsigned int*)p, u, __ATOMIC_RELAXED, __HIP_MEMORY_SCOPE_AGENT);
}

__global__ __launch_bounds__(64) void k_init(int* __restrict__ bar) {
    if (threadIdx.x < 16) bar[threadIdx.x] = 0;
}

__device__ __forceinline__ void gbar(int* bar, int p) {
    asm volatile("s_waitcnt vmcnt(0)" ::: "memory");
    __syncthreads();   // all waves' stores drained (compiler adds waitcnt too)
    if (threadIdx.x == 0) {
        __hip_atomic_fetch_add(&bar[p], 1, __ATOMIC_RELAXED, __HIP_MEMORY_SCOPE_AGENT);
        while (__hip_atomic_load(&bar[p], __ATOMIC_RELAXED, __HIP_MEMORY_SCOPE_AGENT) < NBLK)
            __builtin_amdgcn_s_sleep(2);
    }
    __syncthreads();
}

// MODE 0: Mrow=C stripe; kv=exp(-100*C); store K stripe (normal, L2); x==1
// MODE 1: Mrow=K stripe (normal cached loads); x via LLC loads; update epilogue
// MODE 2: Mrow=C stripe; kv=C*exp(-100*C); x via LLC; cost epilogue
template <int MODE>
__device__ void pass_body(const float4* __restrict__ Mrow,
                          float4* __restrict__ Krow,
                          const float4* __restrict__ xf4,
                          const float* __restrict__ m_sl,
                          float* __restrict__ y_sl,
                          bool first,
                          float* __restrict__ yg,
                          const float* __restrict__ a_sl,
                          float* __restrict__ part_out,
                          float* __restrict__ S_lds,
                          float* __restrict__ c_lds) {
    const int t = threadIdx.x;
    const int w = t >> 6, l = t & 63;
    const int jl = l & 7, bl = l >> 3;
    const int wbeg = w * WPW;

    float4 acc[ROWS];
    #pragma unroll
    for (int r = 0; r < ROWS; ++r) acc[r] = make_float4(0.f, 0.f, 0.f, 0.f);

    // prefetch: K 1 window deep (L2-resident), x 2 windows deep (LLC)
    float4 kn[ROWS], xp[2][4];
    #pragma unroll
    for (int r = 0; r < ROWS; ++r) kn[r] = Mrow[(size_t)r * SNF4 + wbeg * 8 + jl];
    if (MODE != 0) {
        #pragma unroll
        for (int jj = 0; jj < 4; ++jj)
            xp[0][jj] = ldg_llc4(&xf4[(size_t)(wbeg * 32 + jl * 4 + jj) * 8 + bl]);
        #pragma unroll
        for (int jj = 0; jj < 4; ++jj)
            xp[1][jj] = ldg_llc4(&xf4[(size_t)((wbeg + 1) * 32 + jl * 4 + jj) * 8 + bl]);
    }

    #pragma unroll
    for (int q = 0; q < WPW; ++q) {
        const int win = wbeg + q;
        float4 kc[ROWS];
        #pragma unroll
        for (int r = 0; r < ROWS; ++r) kc[r] = kn[r];
        if (q + 1 < WPW) {
            #pragma unroll
            for (int r = 0; r < ROWS; ++r)
                kn[r] = Mrow[(size_t)r * SNF4 + (win + 1) * 8 + jl];
        }
        if (MODE != 0 && q + 2 < WPW) {
            #pragma unroll
            for (int jj = 0; jj < 4; ++jj)
                xp[q & 1][jj] =
                    ldg_llc4(&xf4[(size_t)((win + 2) * 32 + jl * 4 + jj) * 8 + bl]);
        }
        const float4* xc = (MODE != 0) ? xp[(q & 1) ^ 1] : nullptr;
        #pragma unroll
        for (int r = 0; r < ROWS; ++r) {
            if (MODE == 0) {
                float4 kv;
                kv.x = __expf(kc[r].x * -100.f);
                kv.y = __expf(kc[r].y * -100.f);
                kv.z = __expf(kc[r].z * -100.f);
                kv.w = __expf(kc[r].w * -100.f);
                if (bl == 0) Krow[(size_t)r * SNF4 + win * 8 + jl] = kv;
                acc[r].x += (kv.x + kv.y) + (kv.z + kv.w);
            } else {
                float4 kv = kc[r];
                if (MODE == 2) {
                    kv.x *= __expf(kv.x * -100.f);
                    kv.y *= __expf(kv.y * -100.f);
                    kv.z *= __expf(kv.z * -100.f);
                    kv.w *= __expf(kv.w * -100.f);
                }
                fma4(acc[r], kv.x, xc[0]);
                fma4(acc[r], kv.y, xc[1]);
                fma4(acc[r], kv.z, xc[2]);
                fma4(acc[r], kv.w, xc[3]);
            }
        }
    }

    // reduce over the 8 j-lanes
    #pragma unroll
    for (int r = 0; r < ROWS; ++r) {
        float4 a = acc[r];
        #pragma unroll
        for (int off = 1; off <= 4; off <<= 1) {
            a.x += __shfl_down(a.x, off);
            a.y += __shfl_down(a.y, off);
            a.z += __shfl_down(a.z, off);
            a.w += __shfl_down(a.w, off);
        }
        if (MODE == 0) { float s = a.x; a = make_float4(s, s, s, s); }
        acc[r] = a;
    }
    if (jl == 0) {
        #pragma unroll
        for (int r = 0; r < ROWS; ++r)
            *(float4*)&S_lds[w * 288 + r * 32 + bl * 4] = acc[r];
    }
    __syncthreads();

    if (MODE == 2) {
        if (t < 288) {
            float s = 0.f;
            #pragma unroll
            for (int ww = 0; ww < 8; ++ww) s += S_lds[ww * 288 + t];
            c_lds[t] = a_sl[t] * s;
        }
        __syncthreads();
        if (t < 32) {
            float p = 0.f;
            #pragma unroll
            for (int r = 0; r < ROWS; ++r) p += c_lds[r * 32 + t];
            part_out[t] = p;
        }
    } else {
        if (t < 288) {
            float s = 0.f;
            #pragma unroll
            for (int ww = 0; ww < 8; ++ww) s += S_lds[ww * 288 + t];
            const float yo = first ? 1.f : y_sl[t];
            const float yn = m_sl[t] * yo / (yo * s + 1e-6f);
            y_sl[t] = yn;
            stg_llc(&yg[t], yn);     // LLC write-through, no L2 dirty state
        }
        __syncthreads();
    }
}

__global__ __launch_bounds__(NTHR, 2) void k_persist(
        const float* __restrict__ C,
        const float* __restrict__ pred, const float* __restrict__ tgt,
        float* __restrict__ Kws,
        float* __restrict__ ya, float* __restrict__ yb,
        float* __restrict__ psum, float* __restrict__ tsum,
        float* __restrict__ part, int* __restrict__ bar) {
    __shared__ float S_lds[8 * 288];
    __shared__ float c_lds[288];
    __shared__ float m_lds[2][288];
    __shared__ float y_lds[2][288];

    const int blk = blockIdx.x;
    const int r0 = blk * ROWS;
    const int t = threadIdx.x;

    // phase A: per-batch mass sums (blocks 0..63), LLC stores
    if (blk < 64) {
        const int b = blk & 31;
        const float* src = (blk < 32 ? pred : tgt) + (size_t)b * 3 * SN;
        float s = 0.f;
        for (int i = t; i < SN; i += NTHR) s += src[i] + 1e-9f;
        #pragma unroll
        for (int off = 32; off; off >>= 1) s += __shfl_down(s, off);
        if ((t & 63) == 0) c_lds[t >> 6] = s;
        __syncthreads();
        if (t == 0) {
            float tot = 0.f;
            #pragma unroll
            for (int ww = 0; ww < 8; ++ww) tot += c_lds[ww];
            stg_llc(blk < 32 ? &psum[b] : &tsum[b], tot);
        }
    }
    gbar(bar, 0);

    // phase B: block-local m slices (LLC loads of psum/tsum)
    if (t < 288) {
        const int r = t >> 5, b = t & 31;
        const size_t off = (size_t)b * 3 * SN + (r0 + r);
        m_lds[0][t] = (pred[off] + 1e-9f) / ldg_llc(&psum[b]);
        m_lds[1][t] = (tgt[off] + 1e-9f) / ldg_llc(&tsum[b]);
    }
    __syncthreads();

    const float4* Cf4 = (const float4*)C + (size_t)r0 * SNF4;
    float4* Kf4 = (float4*)Kws + (size_t)r0 * SNF4;

    // pass 0: build K (stays in this XCD's L2), S=K*1, a = msrc/(S+1e-6)
    pass_body<0>(Cf4, Kf4, nullptr, m_lds[0], y_lds[0], true,
                 ya + (size_t)r0 * NBAT, nullptr, nullptr, S_lds, c_lds);
    gbar(bar, 1);

    // passes 1..9
    for (int p = 1; p < 10; ++p) {
        const float* xg = (p & 1) ? ya : yb;
        float* yg = (p & 1) ? yb : ya;
        pass_body<1>(Kf4, nullptr, (const float4*)xg, m_lds[p & 1], y_lds[p & 1],
                     p < 2, yg + (size_t)r0 * NBAT, nullptr, nullptr, S_lds, c_lds);
        gbar(bar, 1 + p);
    }

    // cost pass: S = (K.C)*b, part = sum_r a.*S (normal stores; next kernel
    // sees them via the dispatch-boundary release)
    pass_body<2>(Cf4, nullptr, (const float4*)yb, nullptr, nullptr, false,
                 nullptr, y_lds[0], part + (size_t)blk * NBAT, S_lds, c_lds);
}

__global__ __launch_bounds__(256) void k_out(const float* __restrict__ part,
                                             float* __restrict__ out) {
    __shared__ float l[256];
    const int t = threadIdx.x;
    const int b = t & 31, g = t >> 5;
    float s = 0.f;
    for (int k = g; k < NBLK; k += 8) s += part[(size_t)k * NBAT + b];
    l[t] = s;
    __syncthreads();
    if (t < 32) {
        float o = 0.f;
        #pragma unroll
        for (int g2 = 0; g2 < 8; ++g2) o += l[g2 * 32 + t];
        out[t] = o;
    }
}

extern "C" void kernel_launch(void* const* d_in, const int* in_sizes, int n_in,
                              void* d_out, int out_size, void* d_ws, size_t ws_size,
                              hipStream_t stream) {
    const float* pred = (const float*)d_in[0];
    const float* tgt  = (const float*)d_in[1];
    const float* C    = (const float*)d_in[2];
    float* out = (float*)d_out;

    float* ws = (float*)d_ws;
    float* Kws  = ws;                                  // SN*SN
    float* ya   = Kws + (size_t)SN * SN;               // SN*32
    float* yb   = ya + (size_t)SN * NBAT;
    float* psum = yb + (size_t)SN * NBAT;              // 32
    float* tsum = psum + NBAT;                         // 32
    float* part = tsum + NBAT;                         // 256*32
    int*   bar  = (int*)(part + (size_t)NBLK * NBAT);  // 16

    k_init<<<1, 64, 0, stream>>>(bar);
    k_persist<<<NBLK, NTHR, 0, stream>>>(C, pred, tgt, Kws, ya, yb,
                                         psum, tsum, part, bar);
    k_out<<<1, 256, 0, stream>>>(part, out);
}

// Round 6
// 523.919 us; speedup vs baseline: 1.1705x; 1.1705x over previous
//
#include <hip/hip_runtime.h>

// Persistent-kernel Sinkhorn (scaling form), fence-free.
// Key ideas vs r4/r5:
//  - y buffers ROTATE per pass (write ybuf[p], read ybuf[p-1]): reader caches
//    never hold stale copies -> NORMAL cached loads for x (L2-shared per XCD).
//  - y published with relaxed agent-scope atomic-exchange (RMW executes at
//    coherence point; vmcnt(0) drain before barrier arrival => visibility).
//  - hierarchical fence-free grid barrier (16 groups + root), no wbl2/inv.
//  - K = exp(-C/eps) block-private stripe, dirty-resident in own XCD L2.

#define SN 2304
#define SNF4 576
#define NBAT 32
#define ROWS 9
#define NBLK 256
#define NTHR 512
#define WPW 9        // 32-j windows per wave (8 waves x 9 x 32 = 2304)
#define NYBUF 10
#define BARSLOTS 11

__device__ __forceinline__ void fma4(float4& a, float k, const float4 x) {
    a.x = fmaf(k, x.x, a.x);
    a.y = fmaf(k, x.y, a.y);
    a.z = fmaf(k, x.z, a.z);
    a.w = fmaf(k, x.w, a.w);
}

// publish a float at the coherence point (atomic swap, relaxed, agent scope)
__device__ __forceinline__ void stx_llc(float* p, float v) {
    union { float f; unsigned int u; } c;
    c.f = v;
    __hip_atomic_exchange((unsigned int*)p, c.u, __ATOMIC_RELAXED,
                          __HIP_MEMORY_SCOPE_AGENT);
}

__global__ __launch_bounds__(256) void k_init(int* __restrict__ bar) {
    const int t = threadIdx.x;
    if (t < BARSLOTS * 32) bar[t] = 0;
    if (t + 256 < BARSLOTS * 32) bar[t + 256] = 0;
}

// fence-free hierarchical grid barrier; slot p. 16 groups of 16 blocks.
__device__ __forceinline__ void gbar(int* bar, int p) {
    asm volatile("s_waitcnt vmcnt(0)" ::: "memory");   // drain this wave's stores
    __syncthreads();                                    // all waves drained
    if (threadIdx.x == 0) {
        int* slot = bar + p * 32;
        const int g = blockIdx.x & 15;
        int old = __hip_atomic_fetch_add(&slot[g], 1, __ATOMIC_RELAXED,
                                         __HIP_MEMORY_SCOPE_AGENT);
        if (old == 15)
            __hip_atomic_fetch_add(&slot[16], 1, __ATOMIC_RELAXED,
                                   __HIP_MEMORY_SCOPE_AGENT);
        while (__hip_atomic_load(&slot[16], __ATOMIC_RELAXED,
                                 __HIP_MEMORY_SCOPE_AGENT) < 16)
            __builtin_amdgcn_s_sleep(2);
    }
    __syncthreads();
}

// MODE 0: Mrow=C stripe; kv=exp(-100*C); store K stripe (normal, L2); x==1
// MODE 1: Mrow=K stripe (normal cached loads); x normal cached; update epilogue
// MODE 2: Mrow=C stripe; kv=C*exp(-100*C); cost epilogue
template <int MODE>
__device__ void pass_body(const float4* __restrict__ Mrow,
                          float4* __restrict__ Krow,
                          const float4* __restrict__ xf4,
                          const float* __restrict__ m_sl,
                          float* __restrict__ y_sl,
                          bool first,
                          float* __restrict__ yg,
                          const float* __restrict__ a_sl,
                          float* __restrict__ part_out,
                          float* __restrict__ S_lds,
                          float* __restrict__ c_lds) {
    const int t = threadIdx.x;
    const int w = t >> 6, l = t & 63;
    const int jl = l & 7, bl = l >> 3;
    const int wbeg = w * WPW;

    float4 acc[ROWS];
    #pragma unroll
    for (int r = 0; r < ROWS; ++r) acc[r] = make_float4(0.f, 0.f, 0.f, 0.f);

    // prefetch: K 1 window deep (L2-resident), x 2 windows deep
    float4 kn[ROWS], xp[2][4];
    #pragma unroll
    for (int r = 0; r < ROWS; ++r) kn[r] = Mrow[(size_t)r * SNF4 + wbeg * 8 + jl];
    if (MODE != 0) {
        #pragma unroll
        for (int jj = 0; jj < 4; ++jj)
            xp[0][jj] = xf4[(size_t)(wbeg * 32 + jl * 4 + jj) * 8 + bl];
        #pragma unroll
        for (int jj = 0; jj < 4; ++jj)
            xp[1][jj] = xf4[(size_t)((wbeg + 1) * 32 + jl * 4 + jj) * 8 + bl];
    }

    #pragma unroll
    for (int q = 0; q < WPW; ++q) {
        const int win = wbeg + q;
        float4 kc[ROWS];
        #pragma unroll
        for (int r = 0; r < ROWS; ++r) kc[r] = kn[r];
        if (q + 1 < WPW) {
            #pragma unroll
            for (int r = 0; r < ROWS; ++r)
                kn[r] = Mrow[(size_t)r * SNF4 + (win + 1) * 8 + jl];
        }
        if (MODE != 0 && q + 2 < WPW) {
            #pragma unroll
            for (int jj = 0; jj < 4; ++jj)
                xp[q & 1][jj] = xf4[(size_t)((win + 2) * 32 + jl * 4 + jj) * 8 + bl];
        }
        const float4* xc = (MODE != 0) ? xp[(q & 1) ^ 1] : nullptr;
        #pragma unroll
        for (int r = 0; r < ROWS; ++r) {
            if (MODE == 0) {
                float4 kv;
                kv.x = __expf(kc[r].x * -100.f);
                kv.y = __expf(kc[r].y * -100.f);
                kv.z = __expf(kc[r].z * -100.f);
                kv.w = __expf(kc[r].w * -100.f);
                if (bl == 0) Krow[(size_t)r * SNF4 + win * 8 + jl] = kv;
                acc[r].x += (kv.x + kv.y) + (kv.z + kv.w);
            } else {
                float4 kv = kc[r];
                if (MODE == 2) {
                    kv.x *= __expf(kv.x * -100.f);
                    kv.y *= __expf(kv.y * -100.f);
                    kv.z *= __expf(kv.z * -100.f);
                    kv.w *= __expf(kv.w * -100.f);
                }
                fma4(acc[r], kv.x, xc[0]);
                fma4(acc[r], kv.y, xc[1]);
                fma4(acc[r], kv.z, xc[2]);
                fma4(acc[r], kv.w, xc[3]);
            }
        }
    }

    // reduce over the 8 j-lanes
    #pragma unroll
    for (int r = 0; r < ROWS; ++r) {
        float4 a = acc[r];
        #pragma unroll
        for (int off = 1; off <= 4; off <<= 1) {
            a.x += __shfl_down(a.x, off);
            a.y += __shfl_down(a.y, off);
            a.z += __shfl_down(a.z, off);
            a.w += __shfl_down(a.w, off);
        }
        if (MODE == 0) { float s = a.x; a = make_float4(s, s, s, s); }
        acc[r] = a;
    }
    if (jl == 0) {
        #pragma unroll
        for (int r = 0; r < ROWS; ++r)
            *(float4*)&S_lds[w * 288 + r * 32 + bl * 4] = acc[r];
    }
    __syncthreads();

    if (MODE == 2) {
        if (t < 288) {
            float s = 0.f;
            #pragma unroll
            for (int ww = 0; ww < 8; ++ww) s += S_lds[ww * 288 + t];
            c_lds[t] = a_sl[t] * s;
        }
        __syncthreads();
        if (t < 32) {
            float p = 0.f;
            #pragma unroll
            for (int r = 0; r < ROWS; ++r) p += c_lds[r * 32 + t];
            part_out[t] = p;
        }
    } else {
        if (t < 288) {
            float s = 0.f;
            #pragma unroll
            for (int ww = 0; ww < 8; ++ww) s += S_lds[ww * 288 + t];
            const float yo = first ? 1.f : y_sl[t];
            const float yn = m_sl[t] * yo / (yo * s + 1e-6f);
            y_sl[t] = yn;
            stx_llc(&yg[t], yn);   // publish at coherence point
        }
        __syncthreads();           // protect S_lds before next pass
    }
}

__global__ __launch_bounds__(NTHR, 2) void k_persist(
        const float* __restrict__ C,
        const float* __restrict__ pred, const float* __restrict__ tgt,
        float* __restrict__ Kws,
        float* __restrict__ ybase,
        float* __restrict__ psum, float* __restrict__ tsum,
        float* __restrict__ part, int* __restrict__ bar) {
    __shared__ float S_lds[8 * 288];
    __shared__ float c_lds[288];
    __shared__ float m_lds[2][288];
    __shared__ float y_lds[2][288];

    const int blk = blockIdx.x;
    const int r0 = blk * ROWS;
    const int t = threadIdx.x;

    // phase A: per-batch mass sums (blocks 0..63), published via atomic swap
    if (blk < 64) {
        const int b = blk & 31;
        const float* src = (blk < 32 ? pred : tgt) + (size_t)b * 3 * SN;
        float s = 0.f;
        for (int i = t; i < SN; i += NTHR) s += src[i] + 1e-9f;
        #pragma unroll
        for (int off = 32; off; off >>= 1) s += __shfl_down(s, off);
        if ((t & 63) == 0) c_lds[t >> 6] = s;
        __syncthreads();
        if (t == 0) {
            float tot = 0.f;
            #pragma unroll
            for (int ww = 0; ww < 8; ++ww) tot += c_lds[ww];
            stx_llc(blk < 32 ? &psum[b] : &tsum[b], tot);
        }
    }
    gbar(bar, 0);

    // phase B: block-local m slices (normal loads; psum/tsum first touch)
    if (t < 288) {
        const int r = t >> 5, b = t & 31;
        const size_t off = (size_t)b * 3 * SN + (r0 + r);
        m_lds[0][t] = (pred[off] + 1e-9f) / psum[b];
        m_lds[1][t] = (tgt[off] + 1e-9f) / tsum[b];
    }
    __syncthreads();

    const float4* Cf4 = (const float4*)C + (size_t)r0 * SNF4;
    float4* Kf4 = (float4*)Kws + (size_t)r0 * SNF4;

    // pass 0: build K (stays dirty in this XCD's L2), S=K*1, a=msrc/(S+1e-6)
    pass_body<0>(Cf4, Kf4, nullptr, m_lds[0], y_lds[0], true,
                 ybase + (size_t)r0 * NBAT, nullptr, nullptr, S_lds, c_lds);
    gbar(bar, 1);

    // passes 1..9: read ybuf[p-1] (fresh addresses), write ybuf[p]
    for (int p = 1; p < 10; ++p) {
        const float* xg = ybase + (size_t)(p - 1) * SN * NBAT;
        float* yg = ybase + (size_t)p * SN * NBAT + (size_t)r0 * NBAT;
        pass_body<1>(Kf4, nullptr, (const float4*)xg, m_lds[p & 1], y_lds[p & 1],
                     p < 2, yg, nullptr, nullptr, S_lds, c_lds);
        gbar(bar, 1 + p);
    }

    // cost pass: S=(K.C)*b5 (b5 = ybuf[9]), part = sum_r a5 .* S
    pass_body<2>(Cf4, nullptr,
                 (const float4*)(ybase + (size_t)9 * SN * NBAT),
                 nullptr, nullptr, false, nullptr,
                 y_lds[0], part + (size_t)blk * NBAT, S_lds, c_lds);
}

__global__ __launch_bounds__(256) void k_out(const float* __restrict__ part,
                                             float* __restrict__ out) {
    __shared__ float l[256];
    const int t = threadIdx.x;
    const int b = t & 31, g = t >> 5;
    float s = 0.f;
    for (int k = g; k < NBLK; k += 8) s += part[(size_t)k * NBAT + b];
    l[t] = s;
    __syncthreads();
    if (t < 32) {
        float o = 0.f;
        #pragma unroll
        for (int g2 = 0; g2 < 8; ++g2) o += l[g2 * 32 + t];
        out[t] = o;
    }
}

extern "C" void kernel_launch(void* const* d_in, const int* in_sizes, int n_in,
                              void* d_out, int out_size, void* d_ws, size_t ws_size,
                              hipStream_t stream) {
    const float* pred = (const float*)d_in[0];
    const float* tgt  = (const float*)d_in[1];
    const float* C    = (const float*)d_in[2];
    float* out = (float*)d_out;

    float* ws = (float*)d_ws;
    float* Kws   = ws;                                   // SN*SN
    float* ybase = Kws + (size_t)SN * SN;                // 10 * SN*32
    float* psum  = ybase + (size_t)NYBUF * SN * NBAT;    // 32
    float* tsum  = psum + NBAT;                          // 32
    float* part  = tsum + NBAT;                          // 256*32
    int*   bar   = (int*)(part + (size_t)NBLK * NBAT);   // 11*32 ints

    k_init<<<1, 256, 0, stream>>>(bar);
    k_persist<<<NBLK, NTHR, 0, stream>>>(C, pred, tgt, Kws, ybase,
                                         psum, tsum, part, bar);
    k_out<<<1, 256, 0, stream>>>(part, out);
}

// Round 7
// 285.101 us; speedup vs baseline: 2.1510x; 1.8377x over previous
//
#include <hip/hip_runtime.h>

// Sinkhorn (scaling form), multi-dispatch: dispatch boundaries provide free
// cross-XCD coherence (no fences, no agent atomics in hot paths).
//   pass0: K=exp(-C/eps), KC=C.*K stored; S=K*1; a1=m_src/(S+1e-6)
//   pass p: S=K*y_{p-1}; y_p = m .* y_{p-2} ./ (y_{p-2}.*S + 1e-6)
//   pass10: S=KC*b5; atomicAdd out[b] += sum_i a5_i S_i   (out zeroed in k_sums)
// Pass body: 256 blocks x 512 thr, 9 rows/block, NO syncthreads in main loop;
// K 1-deep, x 2-deep register prefetch; all lanes read 128B-coalesced.

#define SN 2304
#define SNF4 576
#define NBAT 32
#define ROWS 9
#define NBLK 256
#define NTHR 512
#define WPW 9        // 32-j windows per wave (8 waves x 9 x 32 = 2304)

__device__ __forceinline__ void fma4(float4& a, float k, const float4 x) {
    a.x = fmaf(k, x.x, a.x);
    a.y = fmaf(k, x.y, a.y);
    a.z = fmaf(k, x.z, a.z);
    a.w = fmaf(k, x.w, a.w);
}

__global__ __launch_bounds__(256) void k_sums(const float* __restrict__ pred,
                                              const float* __restrict__ tgt,
                                              float* __restrict__ psum,
                                              float* __restrict__ tsum,
                                              float* __restrict__ out) {
    const int b = blockIdx.x & 31;
    const bool isP = blockIdx.x < 32;
    const float* src = (isP ? pred : tgt) + (size_t)b * 3 * SN;
    const int t = threadIdx.x;
    float acc = 0.f;
    for (int i = t; i < SN; i += 256) acc += src[i] + 1e-9f;
    #pragma unroll
    for (int off = 32; off; off >>= 1) acc += __shfl_down(acc, off);
    __shared__ float red[4];
    if ((t & 63) == 0) red[t >> 6] = acc;
    __syncthreads();
    if (t == 0) (isP ? psum : tsum)[b] = red[0] + red[1] + red[2] + red[3];
    if (blockIdx.x == 0 && t < NBAT) out[t] = 0.f;   // d_out was poisoned
}

__global__ __launch_bounds__(256) void k_minit(const float* __restrict__ pred,
                                               const float* __restrict__ tgt,
                                               const float* __restrict__ psum,
                                               const float* __restrict__ tsum,
                                               float* __restrict__ msrc,
                                               float* __restrict__ mtgt) {
    const int b = blockIdx.x;
    const float ps = psum[b], ts = tsum[b];
    #pragma unroll
    for (int k = 0; k < 9; ++k) {
        const int i = threadIdx.x + k * 256;
        msrc[(size_t)i * NBAT + b] = (pred[(size_t)b * 3 * SN + i] + 1e-9f) / ps;
        mtgt[(size_t)i * NBAT + b] = (tgt[(size_t)b * 3 * SN + i] + 1e-9f) / ts;
    }
}

// MODE 0: Msrc=C; kv=exp(-100*C); store K and KC=C.*K; x==1; update epilogue
// MODE 1: Msrc=K; x from xg; update epilogue
// MODE 2: Msrc=KC; x from xg; cost epilogue (atomicAdd into out)
template <int MODE>
__global__ __launch_bounds__(NTHR, 2) void k_pass(
        const float* __restrict__ Msrc,
        float* __restrict__ Kout, float* __restrict__ KCout,
        const float* __restrict__ xg,
        const float* __restrict__ mside,
        const float* __restrict__ yoldg,   // null => yold = 1
        float* __restrict__ ynew,
        const float* __restrict__ afin,
        float* __restrict__ out) {
    __shared__ float S_lds[8 * 288];
    __shared__ float c_lds[288];
    __shared__ float m_lds[288];
    __shared__ float yo_lds[288];

    const int t = threadIdx.x;
    const int blk = blockIdx.x;
    const int r0 = blk * ROWS;
    const int w = t >> 6, l = t & 63;
    const int jl = l & 7, bl = l >> 3;
    const int wbeg = w * WPW;

    // stage per-dispatch slices (once, before the sync-free main loop)
    if (t < 288) {
        if (MODE == 2) {
            m_lds[t] = afin[(size_t)r0 * NBAT + t];
        } else {
            m_lds[t] = mside[(size_t)r0 * NBAT + t];
            yo_lds[t] = yoldg ? yoldg[(size_t)r0 * NBAT + t] : 1.f;
        }
    }
    __syncthreads();

    const float4* Mf4 = (const float4*)Msrc + (size_t)r0 * SNF4;
    const float4* xf4 = (const float4*)xg;

    float4 acc[ROWS];
    #pragma unroll
    for (int r = 0; r < ROWS; ++r) acc[r] = make_float4(0.f, 0.f, 0.f, 0.f);

    // prefetch: K 1 window deep, x 2 windows deep
    float4 kn[ROWS], xp[2][4];
    #pragma unroll
    for (int r = 0; r < ROWS; ++r) kn[r] = Mf4[(size_t)r * SNF4 + wbeg * 8 + jl];
    if (MODE != 0) {
        #pragma unroll
        for (int jj = 0; jj < 4; ++jj)
            xp[0][jj] = xf4[(size_t)(wbeg * 32 + jl * 4 + jj) * 8 + bl];
        #pragma unroll
        for (int jj = 0; jj < 4; ++jj)
            xp[1][jj] = xf4[(size_t)((wbeg + 1) * 32 + jl * 4 + jj) * 8 + bl];
    }

    #pragma unroll
    for (int q = 0; q < WPW; ++q) {
        const int win = wbeg + q;
        float4 kc[ROWS];
        #pragma unroll
        for (int r = 0; r < ROWS; ++r) kc[r] = kn[r];
        if (q + 1 < WPW) {
            #pragma unroll
            for (int r = 0; r < ROWS; ++r)
                kn[r] = Mf4[(size_t)r * SNF4 + (win + 1) * 8 + jl];
        }
        if (MODE != 0 && q + 2 < WPW) {
            #pragma unroll
            for (int jj = 0; jj < 4; ++jj)
                xp[q & 1][jj] = xf4[(size_t)((win + 2) * 32 + jl * 4 + jj) * 8 + bl];
        }
        const float4* xc = (MODE != 0) ? xp[(q & 1) ^ 1] : nullptr;
        #pragma unroll
        for (int r = 0; r < ROWS; ++r) {
            if (MODE == 0) {
                const float4 cv = kc[r];
                float4 kv;
                kv.x = __expf(cv.x * -100.f);
                kv.y = __expf(cv.y * -100.f);
                kv.z = __expf(cv.z * -100.f);
                kv.w = __expf(cv.w * -100.f);
                if (bl == 0) {
                    ((float4*)Kout)[(size_t)(r0 + r) * SNF4 + win * 8 + jl] = kv;
                    float4 kcv;
                    kcv.x = cv.x * kv.x; kcv.y = cv.y * kv.y;
                    kcv.z = cv.z * kv.z; kcv.w = cv.w * kv.w;
                    ((float4*)KCout)[(size_t)(r0 + r) * SNF4 + win * 8 + jl] = kcv;
                }
                acc[r].x += (kv.x + kv.y) + (kv.z + kv.w);
            } else {
                fma4(acc[r], kc[r].x, xc[0]);
                fma4(acc[r], kc[r].y, xc[1]);
                fma4(acc[r], kc[r].z, xc[2]);
                fma4(acc[r], kc[r].w, xc[3]);
            }
        }
    }

    // reduce over the 8 j-lanes
    #pragma unroll
    for (int r = 0; r < ROWS; ++r) {
        float4 a = acc[r];
        #pragma unroll
        for (int off = 1; off <= 4; off <<= 1) {
            a.x += __shfl_down(a.x, off);
            a.y += __shfl_down(a.y, off);
            a.z += __shfl_down(a.z, off);
            a.w += __shfl_down(a.w, off);
        }
        if (MODE == 0) { float s = a.x; a = make_float4(s, s, s, s); }
        acc[r] = a;
    }
    if (jl == 0) {
        #pragma unroll
        for (int r = 0; r < ROWS; ++r)
            *(float4*)&S_lds[w * 288 + r * 32 + bl * 4] = acc[r];
    }
    __syncthreads();

    if (MODE == 2) {
        if (t < 288) {
            float s = 0.f;
            #pragma unroll
            for (int ww = 0; ww < 8; ++ww) s += S_lds[ww * 288 + t];
            c_lds[t] = m_lds[t] * s;   // a5 .* S
        }
        __syncthreads();
        if (t < 32) {
            float p = 0.f;
            #pragma unroll
            for (int r = 0; r < ROWS; ++r) p += c_lds[r * 32 + t];
            atomicAdd(&out[t], p);
        }
    } else {
        if (t < 288) {
            float s = 0.f;
            #pragma unroll
            for (int ww = 0; ww < 8; ++ww) s += S_lds[ww * 288 + t];
            const float yo = yo_lds[t];
            ynew[(size_t)r0 * NBAT + t] = m_lds[t] * yo / (yo * s + 1e-6f);
        }
    }
}

extern "C" void kernel_launch(void* const* d_in, const int* in_sizes, int n_in,
                              void* d_out, int out_size, void* d_ws, size_t ws_size,
                              hipStream_t stream) {
    const float* pred = (const float*)d_in[0];
    const float* tgt  = (const float*)d_in[1];
    const float* C    = (const float*)d_in[2];
    float* out = (float*)d_out;

    float* ws = (float*)d_ws;
    float* Kws  = ws;                                   // SN*SN
    float* KCws = Kws + (size_t)SN * SN;                // SN*SN
    float* msrc = KCws + (size_t)SN * SN;               // SN*32
    float* mtgt = msrc + (size_t)SN * NBAT;
    float* yb0  = mtgt + (size_t)SN * NBAT;             // 10 x SN*32
    float* psum = yb0 + (size_t)10 * SN * NBAT;         // 32
    float* tsum = psum + NBAT;                          // 32

    auto ybuf = [&](int p) { return yb0 + (size_t)p * SN * NBAT; };

    k_sums<<<64, 256, 0, stream>>>(pred, tgt, psum, tsum, out);
    k_minit<<<32, 256, 0, stream>>>(pred, tgt, psum, tsum, msrc, mtgt);

    // pass 0: build K/KC, S=K*1, a1 = msrc/(S+1e-6)  -> ybuf0
    k_pass<0><<<NBLK, NTHR, 0, stream>>>(C, Kws, KCws, nullptr, msrc, nullptr,
                                         ybuf(0), nullptr, nullptr);
    // pass 1: S=K*a1, b1 = mtgt/(S+1e-6)  -> ybuf1
    k_pass<1><<<NBLK, NTHR, 0, stream>>>(Kws, nullptr, nullptr, ybuf(0), mtgt,
                                         nullptr, ybuf(1), nullptr, nullptr);
    // passes 2..9: y_p = m .* y_{p-2} ./ (y_{p-2} .* (K y_{p-1}) + 1e-6)
    for (int p = 2; p < 10; ++p) {
        const float* m = (p & 1) ? mtgt : msrc;
        k_pass<1><<<NBLK, NTHR, 0, stream>>>(Kws, nullptr, nullptr, ybuf(p - 1),
                                             m, ybuf(p - 2), ybuf(p),
                                             nullptr, nullptr);
    }
    // pass 10: S=KC*b5 (ybuf9), out[b] += sum_i a5_i*S_i  (a5 = ybuf8)
    k_pass<2><<<NBLK, NTHR, 0, stream>>>(KCws, nullptr, nullptr, ybuf(9),
                                         nullptr, nullptr, nullptr, ybuf(8), out);
}